// Round 1
// baseline (7013.124 us; speedup 1.0000x reference)
//
#include <hip/hip_runtime.h>
#include <hip/hip_bf16.h>

#define BATCH 64
#define TSEQ 2048
#define INF 9
#define H 128
#define G4 512
#define NFC 20

__device__ __forceinline__ float sigf(float x) {
    return 1.0f / (1.0f + __expf(-x));
}
__device__ __forceinline__ float tanh_fast(float x) {
    // tanh(x) = 1 - 2/(e^{2x}+1); saturates correctly at +/-inf
    return 1.0f - 2.0f / (__expf(2.0f * x) + 1.0f);
}

// ---------------- Layer 0 scan: one block per batch row ----------------
__global__ __launch_bounds__(512) void lstm0_scan(
    const float* __restrict__ x, const float* __restrict__ Wih,
    const float* __restrict__ Whh, const float* __restrict__ bih,
    const float* __restrict__ bhh, float* __restrict__ h0out)
{
    const int b = blockIdx.x;
    const int g = threadIdx.x;   // gate index 0..511

    __shared__ float hs[H];
    __shared__ float gates[G4];

    float wih[INF], whh[H];
#pragma unroll
    for (int k = 0; k < INF; k++) wih[k] = Wih[(size_t)g * INF + k];
    const float4* W4 = (const float4*)(Whh + (size_t)g * H);
#pragma unroll
    for (int k4 = 0; k4 < H / 4; k4++) {
        float4 wv = W4[k4];
        whh[4 * k4 + 0] = wv.x; whh[4 * k4 + 1] = wv.y;
        whh[4 * k4 + 2] = wv.z; whh[4 * k4 + 3] = wv.w;
    }
    const float bias = bih[g] + bhh[g];

    float c = 0.f;
    if (g < H) hs[g] = 0.f;

    const float* xb = x + (size_t)b * TSEQ * INF;
    float xr[INF];
#pragma unroll
    for (int k = 0; k < INF; k++) xr[k] = xb[k];
    __syncthreads();

    for (int t = 0; t < TSEQ; t++) {
        float a0 = bias, a1 = 0.f, a2 = 0.f, a3 = 0.f;
#pragma unroll
        for (int k = 0; k < INF; k++) a0 += wih[k] * xr[k];
        // prefetch next x row (broadcast loads, L1-resident)
        if (t + 1 < TSEQ) {
            const float* xn = xb + (size_t)(t + 1) * INF;
#pragma unroll
            for (int k = 0; k < INF; k++) xr[k] = xn[k];
        }
        const float4* h4 = (const float4*)hs;
#pragma unroll
        for (int k4 = 0; k4 < H / 4; k4++) {
            float4 hv = h4[k4];
            a0 += whh[4 * k4 + 0] * hv.x;
            a1 += whh[4 * k4 + 1] * hv.y;
            a2 += whh[4 * k4 + 2] * hv.z;
            a3 += whh[4 * k4 + 3] * hv.w;
        }
        gates[g] = (a0 + a1) + (a2 + a3);
        __syncthreads();
        if (g < H) {
            float ig = sigf(gates[g]);
            float fg = sigf(gates[H + g]);
            float gg = tanh_fast(gates[2 * H + g]);
            float og = sigf(gates[3 * H + g]);
            c = fg * c + ig * gg;
            float h = og * tanh_fast(c);
            hs[g] = h;
            h0out[((size_t)b * TSEQ + t) * H + g] = h;
        }
        __syncthreads();
    }
}

// ---------------- xg1 GEMM: xg1[b, t-t0, :] = h0[b,t,:] @ Wih1^T + bias ----------------
__global__ __launch_bounds__(512) void xg1_gemm(
    const float* __restrict__ h0, const float* __restrict__ Wih1,
    const float* __restrict__ bih, const float* __restrict__ bhh,
    float* __restrict__ xg1, int t0, int tlen)
{
    const int b = blockIdx.x >> 2;
    const int s = blockIdx.x & 3;
    const int g = threadIdx.x;
    const int rows = tlen >> 2;
    const int tstart = t0 + s * rows;

    float w[H];
    const float4* W4 = (const float4*)(Wih1 + (size_t)g * H);
#pragma unroll
    for (int k4 = 0; k4 < H / 4; k4++) {
        float4 wv = W4[k4];
        w[4 * k4 + 0] = wv.x; w[4 * k4 + 1] = wv.y;
        w[4 * k4 + 2] = wv.z; w[4 * k4 + 3] = wv.w;
    }
    const float bias = bih[g] + bhh[g];

    __shared__ float hs[2][H];
    if (g < H) hs[0][g] = h0[((size_t)b * TSEQ + tstart) * H + g];
    __syncthreads();

    for (int r = 0; r < rows; r++) {
        int buf = r & 1;
        if (g < H && (r + 1) < rows)
            hs[buf ^ 1][g] = h0[((size_t)b * TSEQ + tstart + r + 1) * H + g];
        float a0 = bias, a1 = 0.f, a2 = 0.f, a3 = 0.f;
        const float4* h4 = (const float4*)hs[buf];
#pragma unroll
        for (int k4 = 0; k4 < H / 4; k4++) {
            float4 hv = h4[k4];
            a0 += w[4 * k4 + 0] * hv.x;
            a1 += w[4 * k4 + 1] * hv.y;
            a2 += w[4 * k4 + 2] * hv.z;
            a3 += w[4 * k4 + 3] * hv.w;
        }
        xg1[((size_t)b * tlen + (size_t)(s * rows + r)) * G4 + g] = (a0 + a1) + (a2 + a3);
        __syncthreads();
    }
}

// ---------------- Layer 1 scan + fused head ----------------
__global__ __launch_bounds__(512) void lstm1_scan(
    const float* __restrict__ Whh1, const float* __restrict__ xg1,
    const float* __restrict__ fc1w, const float* __restrict__ fc1b,
    const float* __restrict__ fc2w, const float* __restrict__ fc2b,
    float* __restrict__ out, float* __restrict__ state, int t0, int tlen)
{
    const int b = blockIdx.x;
    const int g = threadIdx.x;

    __shared__ float hs[H];
    __shared__ float gates[G4];
    __shared__ float hbuf[64][132];      // 64-step h1 history, padded
    __shared__ float fc1w_s[NFC * 132];  // padded rows
    __shared__ float hfcb[64 * NFC];
    __shared__ float fc2w_s[NFC];
    __shared__ float fc1b_s[NFC];

    float whh[H];
    const float4* W4 = (const float4*)(Whh1 + (size_t)g * H);
#pragma unroll
    for (int k4 = 0; k4 < H / 4; k4++) {
        float4 wv = W4[k4];
        whh[4 * k4 + 0] = wv.x; whh[4 * k4 + 1] = wv.y;
        whh[4 * k4 + 2] = wv.z; whh[4 * k4 + 3] = wv.w;
    }
    for (int i = g; i < NFC * H; i += 512) {
        int r = i >> 7, cidx = i & 127;
        fc1w_s[r * 132 + cidx] = fc1w[i];
    }
    if (g < NFC) { fc2w_s[g] = fc2w[g]; fc1b_s[g] = fc1b[g]; }

    float c = 0.f, h = 0.f;
    if (t0 > 0 && g < H) {
        c = state[b * H + g];
        h = state[BATCH * H + b * H + g];
    }
    if (g < H) hs[g] = h;

    float xgr = xg1[((size_t)b * tlen) * G4 + g];
    const float fc2bias = fc2b[0];
    __syncthreads();

    for (int tt = 0; tt < tlen; tt++) {
        float a0 = xgr, a1 = 0.f, a2 = 0.f, a3 = 0.f;
        if (tt + 1 < tlen) xgr = xg1[((size_t)b * tlen + tt + 1) * G4 + g];
        const float4* h4 = (const float4*)hs;
#pragma unroll
        for (int k4 = 0; k4 < H / 4; k4++) {
            float4 hv = h4[k4];
            a0 += whh[4 * k4 + 0] * hv.x;
            a1 += whh[4 * k4 + 1] * hv.y;
            a2 += whh[4 * k4 + 2] * hv.z;
            a3 += whh[4 * k4 + 3] * hv.w;
        }
        gates[g] = (a0 + a1) + (a2 + a3);
        __syncthreads();
        if (g < H) {
            float ig = sigf(gates[g]);
            float fg = sigf(gates[H + g]);
            float gg = tanh_fast(gates[2 * H + g]);
            float og = sigf(gates[3 * H + g]);
            c = fg * c + ig * gg;
            h = og * tanh_fast(c);
            hs[g] = h;
            hbuf[tt & 63][g] = h;
        }
        __syncthreads();

        if ((tt & 63) == 63) {
            // batched head over the last 64 timesteps: 64*20 = 1280 fc1 dots
#pragma unroll
            for (int p = 0; p < 3; p++) {
                int task = p * 512 + g;
                if (task < 64 * NFC) {
                    int sidx = task / NFC;
                    int k = task - sidx * NFC;
                    float b0 = fc1b_s[k], b1 = 0.f, b2 = 0.f, b3 = 0.f;
                    const float4* hr = (const float4*)(&hbuf[sidx][0]);
                    const float4* wr = (const float4*)(&fc1w_s[k * 132]);
#pragma unroll
                    for (int k4 = 0; k4 < H / 4; k4++) {
                        float4 hv = hr[k4];
                        float4 wv = wr[k4];
                        b0 += wv.x * hv.x; b1 += wv.y * hv.y;
                        b2 += wv.z * hv.z; b3 += wv.w * hv.w;
                    }
                    hfcb[task] = tanh_fast((b0 + b1) + (b2 + b3));
                }
            }
            __syncthreads();
            if (g < 64) {
                float o = fc2bias;
#pragma unroll
                for (int k = 0; k < NFC; k++) o += fc2w_s[k] * hfcb[g * NFC + k];
                int tglob = t0 + tt - 63 + g;
                out[(size_t)b * TSEQ + tglob] = o;
            }
            __syncthreads();
        }
    }
    if (g < H) {
        state[b * H + g] = c;
        state[BATCH * H + b * H + g] = h;
    }
}

extern "C" void kernel_launch(void* const* d_in, const int* in_sizes, int n_in,
                              void* d_out, int out_size, void* d_ws, size_t ws_size,
                              hipStream_t stream) {
    const float* x    = (const float*)d_in[0];
    const float* Wih0 = (const float*)d_in[1];
    const float* Whh0 = (const float*)d_in[2];
    const float* bih0 = (const float*)d_in[3];
    const float* bhh0 = (const float*)d_in[4];
    const float* Wih1 = (const float*)d_in[5];
    const float* Whh1 = (const float*)d_in[6];
    const float* bih1 = (const float*)d_in[7];
    const float* bhh1 = (const float*)d_in[8];
    const float* fc1w = (const float*)d_in[9];
    const float* fc1b = (const float*)d_in[10];
    const float* fc2w = (const float*)d_in[11];
    const float* fc2b = (const float*)d_in[12];
    float* out = (float*)d_out;

    char* ws = (char*)d_ws;
    const size_t h0_bytes = (size_t)BATCH * TSEQ * H * 4;          // 64 MB
    const size_t state_bytes = (size_t)2 * BATCH * H * 4;          // 64 KB
    float* h0    = (float*)ws;
    float* state = (float*)(ws + h0_bytes);
    float* xg1   = (float*)(ws + h0_bytes + state_bytes);

    // pick the largest time-chunk whose xg1 buffer fits in the workspace
    int tlen = 64;
    const int cands[4] = {2048, 512, 128, 64};
    for (int i = 0; i < 4; i++) {
        size_t need = h0_bytes + state_bytes + (size_t)BATCH * cands[i] * G4 * 4;
        if (ws_size >= need) { tlen = cands[i]; break; }
    }

    lstm0_scan<<<BATCH, 512, 0, stream>>>(x, Wih0, Whh0, bih0, bhh0, h0);

    const int nch = TSEQ / tlen;
    for (int ci = 0; ci < nch; ci++) {
        xg1_gemm<<<256, 512, 0, stream>>>(h0, Wih1, bih1, bhh1, xg1, ci * tlen, tlen);
        lstm1_scan<<<BATCH, 512, 0, stream>>>(Whh1, xg1, fc1w, fc1b, fc2w, fc2b,
                                              out, state, ci * tlen, tlen);
    }
}